// Round 21
// baseline (68.948 us; speedup 1.0000x reference)
//
#include <hip/hip_runtime.h>
#include <math.h>

#define NUM_FREQS   64
#define NUM_BINS    128
#define NUM_QUERIES 32768
#define HEAD_DIM    128
#define EPS         1e-8f
#define NQB         16   // queries per block (4 waves x 4 j each)
#define QROW        52   // floats per f-row: 4 waves x 12 + 4 pad (16B-aligned)

// ---------------------------------------------------------------------------
// Prep (probe only), bin-pair layout:
//   probeP[(f*64+l)*2 + 0] = { -2Pr, -2Pi, Pr^2+Pi^2, -softplus }   bin = l
//   probeP[(f*64+l)*2 + 1] = same for bin = l+64
//   probeW[f*64+l]         = { mw(l), mw(l+64) }
// ---------------------------------------------------------------------------
__global__ void prep_probe(const float* __restrict__ rp,
                           const float* __restrict__ wraw,
                           const float* __restrict__ mw,
                           float4* __restrict__ probeP,
                           float2* __restrict__ probeW) {
    int idx = blockIdx.x * 256 + threadIdx.x;    // idx = f*128 + b
    if (idx >= NUM_FREQS * NUM_BINS) return;
    int f = idx >> 7;
    int b = idx & 127;
    int l = b & 63, half = b >> 6;
    float pr = rp[b * HEAD_DIM + f];
    float pi = rp[b * HEAD_DIM + NUM_FREQS + f];
    float w  = wraw[b * NUM_FREQS + f];
    float sp = fmaxf(w, 0.0f) + log1pf(expf(-fabsf(w)));   // stable softplus
    probeP[(f * 64 + l) * 2 + half] =
        make_float4(-2.0f * pr, -2.0f * pi, fmaf(pr, pr, pi * pi), -sp);
    reinterpret_cast<float*>(&probeW[f * 64 + l])[half] = mw[b * NUM_FREQS + f];
}

// ---------------------------------------------------------------------------
// Main: block = 256 threads (4 waves); block owns 16 queries; wave w owns
// j in [4w, 4w+4); lane covers bins (lane, lane+64) -> 8 outputs per lane.
// Merged LDS row per (f, wave): {q0q1 | q2q3 | qm0..3} = 3x b128 from one
// base (+0/+16/+32). Strided-dim q-prep: thread c loads dims {c,c+32,c+64,
// c+96} (coalesced b32) -> owns real+imag of freqs c, c+32 -> computes qm
// inline; ONE scatter pass, one __syncthreads, <=4-way scatter banks.
// Probe: bin-pair rows -> 2x b128 (one ptr, offset:16) + 1x b64 for mw-pair.
// Main loop: R20's hand modulo-2 ping-pong (sets A/B), expanded distance
// s = C'' + qm^2 - 2Pr*qr - 2Pi*qi, v_sqrt_f32, sched_barrier(0) phases.
// ---------------------------------------------------------------------------
__global__ __launch_bounds__(256, 4) void main_kernel(
        const float4* __restrict__ probeP,
        const float2* __restrict__ probeW,
        const float*  __restrict__ Q,
        const float*  __restrict__ bias,
        float*        __restrict__ out) {
    __shared__ __align__(16) float srq[(NUM_FREQS + 1) * QROW];  // 13.2 KB

    const int tid   = threadIdx.x;
    const int qbase = blockIdx.x * NQB;

    // ---- in-block q-prep: single pass ----
    {
        const int c  = tid & 31;
        const int r1 = tid >> 5;        // query row 0..7
        const int r2 = r1 + 8;          // query row 8..15
        const float* Q1 = Q + (size_t)(qbase + r1) * HEAD_DIM + c;
        const float* Q2 = Q + (size_t)(qbase + r2) * HEAD_DIM + c;
        float a1[4], a2[4];
        #pragma unroll
        for (int k = 0; k < 4; k++) {   // dims c, c+32, c+64, c+96 (coalesced)
            a1[k] = Q1[32 * k];
            a2[k] = Q2[32 * k];
        }
        float s1 = fmaf(a1[0], a1[0], fmaf(a1[1], a1[1],
                   fmaf(a1[2], a1[2], a1[3] * a1[3])));
        float s2 = fmaf(a2[0], a2[0], fmaf(a2[1], a2[1],
                   fmaf(a2[2], a2[2], a2[3] * a2[3])));
        #pragma unroll
        for (int off = 1; off < 32; off <<= 1) {  // reduce within 32-lane group
            s1 += __shfl_xor(s1, off);
            s2 += __shfl_xor(s2, off);
        }
        float inv1 = 1.0f / (__builtin_amdgcn_sqrtf(s1) + EPS);
        float inv2 = 1.0f / (__builtin_amdgcn_sqrtf(s2) + EPS);

        // cell writer: (f, j) <- {qr, qi} and qm (banks <=4-way across wave)
        #define PUT_CELL(ff, jj_, qr_, qi_)                                   \
        {                                                                     \
            int w_ = (jj_) >> 2, j_ = (jj_) & 3;                              \
            float* p_ = srq + (ff) * QROW + w_ * 12;                          \
            *reinterpret_cast<float2*>(p_ + ((j_ >> 1) << 2) + ((j_ & 1) << 1)) \
                = make_float2(qr_, qi_);                                      \
            p_[8 + j_] = __builtin_amdgcn_sqrtf(                              \
                fmaf(qr_, qr_, fmaf(qi_, qi_, EPS)));                         \
        }
        // row r1: freq c -> (a1[0], a1[2]); freq c+32 -> (a1[1], a1[3])
        PUT_CELL(c,      r1, a1[0] * inv1, a1[2] * inv1);
        PUT_CELL(c + 32, r1, a1[1] * inv1, a1[3] * inv1);
        PUT_CELL(c,      r2, a2[0] * inv2, a2[2] * inv2);
        PUT_CELL(c + 32, r2, a2[1] * inv2, a2[3] * inv2);
        #undef PUT_CELL
    }
    __syncthreads();

    const int lane = tid & 63;
    const int wave = tid >> 6;
    const int jb   = wave * 4;               // this wave's j-chunk base

    float b0 = bias[lane];
    float b1 = bias[64 + lane];

    float acc0[4], acc1[4];
    #pragma unroll
    for (int p = 0; p < 4; p++) { acc0[p] = 0.0f; acc1[p] = 0.0f; }

    const float*  sqp = srq + wave * 12;     // walks +QROW per f
    const float4* pP  = probeP + lane * 2;   // walks +128 per f
    const float2* pW  = probeW + lane;       // walks +64 per f

// compute one f using a named register set (4 j x 2 bins)
#define CSTEP(P0_, P1_, ww_, r01_, r23_, qm_)                                \
    {                                                                        \
        const float qrv[4] = { r01_.x, r01_.z, r23_.x, r23_.z };             \
        const float qiv[4] = { r01_.y, r01_.w, r23_.y, r23_.w };             \
        const float qmv[4] = { qm_.x, qm_.y, qm_.z, qm_.w };                 \
        _Pragma("unroll")                                                    \
        for (int p = 0; p < 4; p++) {                                        \
            float qr = qrv[p], qi = qiv[p], qm = qmv[p];                     \
            float a0 = fmaf(qm, qm, P0_.z);                                  \
            a0 = fmaf(P0_.x, qr, a0);                                        \
            a0 = fmaf(P0_.y, qi, a0);                                        \
            float d0 = __builtin_amdgcn_sqrtf(a0);                           \
            acc0[p] = fmaf(d0, P0_.w, fmaf(qm, ww_.x, acc0[p]));             \
            float a1 = fmaf(qm, qm, P1_.z);                                  \
            a1 = fmaf(P1_.x, qr, a1);                                        \
            a1 = fmaf(P1_.y, qi, a1);                                        \
            float d1 = __builtin_amdgcn_sqrtf(a1);                           \
            acc1[p] = fmaf(d1, P1_.w, fmaf(qm, ww_.y, acc1[p]));             \
        }                                                                    \
    }

    // Prologue: set A <- f = 0.
    float4 A_P0 = pP[0], A_P1 = pP[1];
    float2 A_ww = pW[0];
    float4 A_r01 = *reinterpret_cast<const float4*>(sqp);
    float4 A_r23 = *reinterpret_cast<const float4*>(sqp + 4);
    float4 A_qm  = *reinterpret_cast<const float4*>(sqp + 8);
    sqp += QROW; pP += 128; pW += 64;

    #pragma unroll 2
    for (int g = 0; g < NUM_FREQS / 2; ++g) {
        // ---- issue set B <- f = 2g+1 ----
        float4 B_P0 = pP[0], B_P1 = pP[1];
        float2 B_ww = pW[0];
        float4 B_r01 = *reinterpret_cast<const float4*>(sqp);
        float4 B_r23 = *reinterpret_cast<const float4*>(sqp + 4);
        float4 B_qm  = *reinterpret_cast<const float4*>(sqp + 8);
        sqp += QROW; pP += 128; pW += 64;
        __builtin_amdgcn_sched_barrier(0);
        // ---- compute A (f = 2g) ----
        CSTEP(A_P0, A_P1, A_ww, A_r01, A_r23, A_qm);

        // ---- issue set A <- f = 2g+2 (g=31: guard row / probeW margin) ----
        A_P0 = pP[0]; A_P1 = pP[1];
        A_ww = pW[0];
        A_r01 = *reinterpret_cast<const float4*>(sqp);
        A_r23 = *reinterpret_cast<const float4*>(sqp + 4);
        A_qm  = *reinterpret_cast<const float4*>(sqp + 8);
        sqp += QROW; pP += 128; pW += 64;
        __builtin_amdgcn_sched_barrier(0);
        // ---- compute B (f = 2g+1) ----
        CSTEP(B_P0, B_P1, B_ww, B_r01, B_r23, B_qm);
    }
#undef CSTEP

    #pragma unroll
    for (int p = 0; p < 4; p++) {
        size_t row = (size_t)(qbase + jb + p) * NUM_BINS;
        out[row + lane]      = acc0[p] + b0;     // coalesced
        out[row + 64 + lane] = acc1[p] + b1;     // coalesced
    }
}

// ---------------------------------------------------------------------------
// Fallback (only if ws_size is too small): fully self-contained, slower.
// ---------------------------------------------------------------------------
__global__ void fallback_kernel(const float* __restrict__ Q,
                                const float* __restrict__ rp,
                                const float* __restrict__ wraw,
                                const float* __restrict__ mw,
                                const float* __restrict__ bias,
                                float* __restrict__ out) {
    __shared__ float qn[HEAD_DIM];
    __shared__ float qmag[NUM_FREQS];
    __shared__ float red[NUM_BINS];
    const int t = threadIdx.x;
    const int q = blockIdx.x;

    float v = Q[(size_t)q * HEAD_DIM + t];
    red[t] = v * v;
    __syncthreads();
    for (int s = 64; s > 0; s >>= 1) {
        if (t < s) red[t] += red[t + s];
        __syncthreads();
    }
    float inv = 1.0f / (__builtin_amdgcn_sqrtf(red[0]) + EPS);
    qn[t] = v * inv;
    __syncthreads();
    if (t < NUM_FREQS) {
        float a = qn[t], c = qn[t + NUM_FREQS];
        qmag[t] = __builtin_amdgcn_sqrtf(fmaf(a, a, fmaf(c, c, EPS)));
    }
    __syncthreads();

    const int b = t;
    float acc = 0.0f;
    for (int f = 0; f < NUM_FREQS; f++) {
        float pr = rp[(size_t)b * HEAD_DIM + f];
        float pi = rp[(size_t)b * HEAD_DIM + NUM_FREQS + f];
        float w  = wraw[(size_t)b * NUM_FREQS + f];
        float ew = -(fmaxf(w, 0.0f) + log1pf(expf(-fabsf(w))));
        float er = pr - qn[f];
        float ei = pi - qn[f + NUM_FREQS];
        float d  = __builtin_amdgcn_sqrtf(fmaf(er, er, fmaf(ei, ei, EPS)));
        acc = fmaf(d, ew, fmaf(qmag[f], mw[(size_t)b * NUM_FREQS + f], acc));
    }
    out[(size_t)q * NUM_BINS + b] = acc + bias[b];
}

// ---------------------------------------------------------------------------
extern "C" void kernel_launch(void* const* d_in, const int* in_sizes, int n_in,
                              void* d_out, int out_size, void* d_ws, size_t ws_size,
                              hipStream_t stream) {
    const float* Q    = (const float*)d_in[0];
    const float* rp   = (const float*)d_in[1];
    const float* wraw = (const float*)d_in[2];
    const float* mw   = (const float*)d_in[3];
    const float* bias = (const float*)d_in[4];
    float* out = (float*)d_out;

    const size_t pPBytes = (size_t)NUM_FREQS * 64 * 2 * sizeof(float4); // 128 KiB
    const size_t pWBytes = (size_t)NUM_FREQS * 64 * sizeof(float2);     //  32 KiB
    const size_t need    = pPBytes + pWBytes + 8192;  // + margin for f=64 prefetch

    if (ws_size >= need) {
        float4* probeP = (float4*)d_ws;
        float2* probeW = (float2*)((char*)d_ws + pPBytes);

        hipLaunchKernelGGL(prep_probe, dim3(32), dim3(256), 0, stream,
                           rp, wraw, mw, probeP, probeW);
        hipLaunchKernelGGL(main_kernel, dim3(NUM_QUERIES / NQB), dim3(256), 0,
                           stream, probeP, probeW, Q, bias, out);
    } else {
        hipLaunchKernelGGL(fallback_kernel, dim3(NUM_QUERIES), dim3(NUM_BINS), 0,
                           stream, Q, rp, wraw, mw, bias, out);
    }
}

// Round 22
// 66.014 us; speedup vs baseline: 1.0444x; 1.0444x over previous
//
#include <hip/hip_runtime.h>
#include <math.h>

#define NUM_FREQS   64
#define NUM_BINS    128
#define NUM_QUERIES 32768
#define HEAD_DIM    128
#define EPS         1e-8f
#define NQB         16   // queries per block (4 waves x 4 j each)
#define SRP         (NQB + 1)   // padded sri row stride (17 float2) -> scatter 4-way

// ---------------------------------------------------------------------------
// Prep (probe only): probeA[f*128+b] = { -2Pr, -2Pi, Pr^2+Pi^2, -softplus }
//                    probeM[f*128+b] = mw
// ---------------------------------------------------------------------------
__global__ void prep_probe(const float* __restrict__ rp,
                           const float* __restrict__ wraw,
                           const float* __restrict__ mw,
                           float4* __restrict__ probeA,
                           float*  __restrict__ probeM) {
    int idx = blockIdx.x * 256 + threadIdx.x;    // idx = f*128 + b
    if (idx >= NUM_FREQS * NUM_BINS) return;
    int f = idx >> 7;
    int b = idx & 127;
    float pr = rp[b * HEAD_DIM + f];
    float pi = rp[b * HEAD_DIM + NUM_FREQS + f];
    float w  = wraw[b * NUM_FREQS + f];
    float sp = fmaxf(w, 0.0f) + log1pf(expf(-fabsf(w)));   // stable softplus
    probeA[idx] = make_float4(-2.0f * pr, -2.0f * pi,
                              fmaf(pr, pr, pi * pi), -sp);
    probeM[idx] = mw[b * NUM_FREQS + f];
}

// ---------------------------------------------------------------------------
// Main: block = 256 threads (4 waves); block owns 16 queries; wave w owns
// j in [4w, 4w+4); lane covers bins (lane, lane+64) -> 8 outputs per lane.
// In-block q-prep (padded sri, 4-way scatter). Main loop: expanded distance
// s = C'' + qm^2 - 2Pr*qr - 2Pi*qi, v_sqrt_f32.
// DEPTH-2 MODULO-3 SCHEDULE: three statically-named sets A/B/C; each set is
// issued TWO compute-phases (~224 cy) before consumption, fully covering
// LDS/L1 latency under load (R20's depth-1 gave only ~112 cy of cover).
//   issue C(f+2); SB; compute A(f);
//   issue A(f+3); SB; compute B(f+1);
//   issue B(f+4); SB; compute C(f+2);
// ---------------------------------------------------------------------------
__global__ __launch_bounds__(256, 4) void main_kernel(
        const float4* __restrict__ probeA,
        const float*  __restrict__ probeM,
        const float*  __restrict__ Q,
        const float*  __restrict__ bias,
        float*        __restrict__ out) {
    __shared__ float2 sri[NUM_FREQS + 1][SRP];   // padded, +1 guard row
    __shared__ float  sqm[NUM_FREQS + 1][NQB];   // linear, +1 guard row

    const int tid   = threadIdx.x;
    const int qbase = blockIdx.x * NQB;

    // ---- in-block q-prep ----
    {
        const float4* Qb = reinterpret_cast<const float4*>(Q + (size_t)qbase * HEAD_DIM);
        float4 v1 = Qb[tid];
        float4 v2 = Qb[tid + 256];
        const int c  = tid & 31;
        const int r1 = tid >> 5;
        const int r2 = r1 + 8;

        float s1 = fmaf(v1.x, v1.x, fmaf(v1.y, v1.y, fmaf(v1.z, v1.z, v1.w * v1.w)));
        float s2 = fmaf(v2.x, v2.x, fmaf(v2.y, v2.y, fmaf(v2.z, v2.z, v2.w * v2.w)));
        #pragma unroll
        for (int off = 1; off < 32; off <<= 1) {   // reduce within 32-lane group
            s1 += __shfl_xor(s1, off);
            s2 += __shfl_xor(s2, off);
        }
        float inv1 = 1.0f / (__builtin_amdgcn_sqrtf(s1) + EPS);
        float inv2 = 1.0f / (__builtin_amdgcn_sqrtf(s2) + EPS);

        const float a1[4] = { v1.x, v1.y, v1.z, v1.w };
        const float a2[4] = { v2.x, v2.y, v2.z, v2.w };
        if (c < 16) {                          // real parts: rows d = 4c+k
            #pragma unroll
            for (int k = 0; k < 4; k++) {
                int row = 4 * c + k;
                sri[row][r1].x = a1[k] * inv1;
                sri[row][r2].x = a2[k] * inv2;
            }
        } else {                               // imag parts: rows 4(c-16)+k
            #pragma unroll
            for (int k = 0; k < 4; k++) {
                int row = 4 * (c - 16) + k;
                sri[row][r1].y = a1[k] * inv1;
                sri[row][r2].y = a2[k] * inv2;
            }
        }
    }
    __syncthreads();
    #pragma unroll
    for (int i = 0; i < 4; i++) {
        int e = i * 256 + tid;
        int f = e >> 4, j = e & 15;
        float2 ri = sri[f][j];
        sqm[f][j] = __builtin_amdgcn_sqrtf(fmaf(ri.x, ri.x, fmaf(ri.y, ri.y, EPS)));
    }
    __syncthreads();

    const int lane = tid & 63;
    const int wave = tid >> 6;
    const int jb   = wave * 4;               // this wave's j-chunk base

    float b0 = bias[lane];
    float b1 = bias[64 + lane];

    float acc0[4], acc1[4];
    #pragma unroll
    for (int p = 0; p < 4; p++) { acc0[p] = 0.0f; acc1[p] = 0.0f; }

    const float4* pA = probeA + lane;        // walks +128 float4 per f
    const float*  pM = probeM + lane;

// compute one f using a named register set (4 j x 2 bins)
#define CSTEP(P0_, P1_, w0_, w1_, qa_, qb_, qc_, qd_, qm_)                   \
    {                                                                        \
        const float qrv[4] = { qa_.x, qb_.x, qc_.x, qd_.x };                 \
        const float qiv[4] = { qa_.y, qb_.y, qc_.y, qd_.y };                 \
        const float qmv[4] = { qm_.x, qm_.y, qm_.z, qm_.w };                 \
        _Pragma("unroll")                                                    \
        for (int p = 0; p < 4; p++) {                                        \
            float qr = qrv[p], qi = qiv[p], qm = qmv[p];                     \
            float a0 = fmaf(qm, qm, P0_.z);                                  \
            a0 = fmaf(P0_.x, qr, a0);                                        \
            a0 = fmaf(P0_.y, qi, a0);                                        \
            float d0 = __builtin_amdgcn_sqrtf(a0);                           \
            acc0[p] = fmaf(d0, P0_.w, fmaf(qm, w0_, acc0[p]));               \
            float a1 = fmaf(qm, qm, P1_.z);                                  \
            a1 = fmaf(P1_.x, qr, a1);                                        \
            a1 = fmaf(P1_.y, qi, a1);                                        \
            float d1 = __builtin_amdgcn_sqrtf(a1);                           \
            acc1[p] = fmaf(d1, P1_.w, fmaf(qm, w1_, acc1[p]));               \
        }                                                                    \
    }

#define LOADSET(S, ff)                                                       \
        S##_P0 = pA[0]; S##_P1 = pA[64];                                     \
        S##_w0 = pM[0]; S##_w1 = pM[64];                                     \
        S##_q0 = sri[ff][jb];     S##_q1 = sri[ff][jb + 1];                  \
        S##_q2 = sri[ff][jb + 2]; S##_q3 = sri[ff][jb + 3];                  \
        S##_qm = *reinterpret_cast<const float4*>(&sqm[ff][jb]);             \
        pA += NUM_BINS; pM += NUM_BINS;

    // Prologue: A <- f=0, B <- f=1.
    float4 A_P0, A_P1, B_P0, B_P1, C_P0, C_P1;
    float  A_w0, A_w1, B_w0, B_w1, C_w0, C_w1;
    float2 A_q0, A_q1, A_q2, A_q3, B_q0, B_q1, B_q2, B_q3, C_q0, C_q1, C_q2, C_q3;
    float4 A_qm, B_qm, C_qm;
    LOADSET(A, 0)
    LOADSET(B, 1)

    for (int g = 0; g < 21; ++g) {           // f = 3g .. 3g+2, covers 0..62
        const int fc = 3 * g + 2;
        // ---- issue C <- fc ----
        LOADSET(C, fc)
        __builtin_amdgcn_sched_barrier(0);
        CSTEP(A_P0, A_P1, A_w0, A_w1, A_q0, A_q1, A_q2, A_q3, A_qm);   // f=3g

        // ---- issue A <- fc+1 ----
        LOADSET(A, fc + 1)
        __builtin_amdgcn_sched_barrier(0);
        CSTEP(B_P0, B_P1, B_w0, B_w1, B_q0, B_q1, B_q2, B_q3, B_qm);   // f=3g+1

        // ---- issue B <- fc+2 (g=20: row 64 = guard / margin, unused) ----
        LOADSET(B, fc + 2)
        __builtin_amdgcn_sched_barrier(0);
        CSTEP(C_P0, C_P1, C_w0, C_w1, C_q0, C_q1, C_q2, C_q3, C_qm);   // f=3g+2
    }
    // Epilogue: f = 63 (loaded as A <- 63 in the last iteration).
    CSTEP(A_P0, A_P1, A_w0, A_w1, A_q0, A_q1, A_q2, A_q3, A_qm);
#undef LOADSET
#undef CSTEP

    #pragma unroll
    for (int p = 0; p < 4; p++) {
        size_t row = (size_t)(qbase + jb + p) * NUM_BINS;
        out[row + lane]      = acc0[p] + b0;     // coalesced
        out[row + 64 + lane] = acc1[p] + b1;     // coalesced
    }
}

// ---------------------------------------------------------------------------
// Fallback (only if ws_size is too small): fully self-contained, slower.
// ---------------------------------------------------------------------------
__global__ void fallback_kernel(const float* __restrict__ Q,
                                const float* __restrict__ rp,
                                const float* __restrict__ wraw,
                                const float* __restrict__ mw,
                                const float* __restrict__ bias,
                                float* __restrict__ out) {
    __shared__ float qn[HEAD_DIM];
    __shared__ float qmag[NUM_FREQS];
    __shared__ float red[NUM_BINS];
    const int t = threadIdx.x;
    const int q = blockIdx.x;

    float v = Q[(size_t)q * HEAD_DIM + t];
    red[t] = v * v;
    __syncthreads();
    for (int s = 64; s > 0; s >>= 1) {
        if (t < s) red[t] += red[t + s];
        __syncthreads();
    }
    float inv = 1.0f / (__builtin_amdgcn_sqrtf(red[0]) + EPS);
    qn[t] = v * inv;
    __syncthreads();
    if (t < NUM_FREQS) {
        float a = qn[t], c = qn[t + NUM_FREQS];
        qmag[t] = __builtin_amdgcn_sqrtf(fmaf(a, a, fmaf(c, c, EPS)));
    }
    __syncthreads();

    const int b = t;
    float acc = 0.0f;
    for (int f = 0; f < NUM_FREQS; f++) {
        float pr = rp[(size_t)b * HEAD_DIM + f];
        float pi = rp[(size_t)b * HEAD_DIM + NUM_FREQS + f];
        float w  = wraw[(size_t)b * NUM_FREQS + f];
        float ew = -(fmaxf(w, 0.0f) + log1pf(expf(-fabsf(w))));
        float er = pr - qn[f];
        float ei = pi - qn[f + NUM_FREQS];
        float d  = __builtin_amdgcn_sqrtf(fmaf(er, er, fmaf(ei, ei, EPS)));
        acc = fmaf(d, ew, fmaf(qmag[f], mw[(size_t)b * NUM_FREQS + f], acc));
    }
    out[(size_t)q * NUM_BINS + b] = acc + bias[b];
}

// ---------------------------------------------------------------------------
extern "C" void kernel_launch(void* const* d_in, const int* in_sizes, int n_in,
                              void* d_out, int out_size, void* d_ws, size_t ws_size,
                              hipStream_t stream) {
    const float* Q    = (const float*)d_in[0];
    const float* rp   = (const float*)d_in[1];
    const float* wraw = (const float*)d_in[2];
    const float* mw   = (const float*)d_in[3];
    const float* bias = (const float*)d_in[4];
    float* out = (float*)d_out;

    const size_t pABytes = (size_t)NUM_FREQS * NUM_BINS * sizeof(float4);  // 128 KiB
    const size_t pMBytes = (size_t)NUM_FREQS * NUM_BINS * sizeof(float);   //  32 KiB
    const size_t need    = pABytes + pMBytes + 8192;   // + margin for f=64 prefetch

    if (ws_size >= need) {
        float4* probeA = (float4*)d_ws;
        float*  probeM = (float*)((char*)d_ws + pABytes);

        hipLaunchKernelGGL(prep_probe, dim3(32), dim3(256), 0, stream,
                           rp, wraw, mw, probeA, probeM);
        hipLaunchKernelGGL(main_kernel, dim3(NUM_QUERIES / NQB), dim3(256), 0,
                           stream, probeA, probeM, Q, bias, out);
    } else {
        hipLaunchKernelGGL(fallback_kernel, dim3(NUM_QUERIES), dim3(NUM_BINS), 0,
                           stream, Q, rp, wraw, mw, bias, out);
    }
}

// Round 23
// 64.318 us; speedup vs baseline: 1.0720x; 1.0264x over previous
//
#include <hip/hip_runtime.h>
#include <math.h>

#define NUM_FREQS   64
#define NUM_BINS    128
#define NUM_QUERIES 32768
#define HEAD_DIM    128
#define EPS         1e-8f
#define NQB         16   // queries per block (4 waves x 4 j each)
#define SRP         (NQB + 1)   // padded sri row stride (17 float2) -> scatter 4-way

// ---------------------------------------------------------------------------
// Prep (probe only): probeA[f*128+b] = { -2Pr, -2Pi, Pr^2+Pi^2, -softplus }
//                    probeM[f*128+b] = mw
// ---------------------------------------------------------------------------
__global__ void prep_probe(const float* __restrict__ rp,
                           const float* __restrict__ wraw,
                           const float* __restrict__ mw,
                           float4* __restrict__ probeA,
                           float*  __restrict__ probeM) {
    int idx = blockIdx.x * 256 + threadIdx.x;    // idx = f*128 + b
    if (idx >= NUM_FREQS * NUM_BINS) return;
    int f = idx >> 7;
    int b = idx & 127;
    float pr = rp[b * HEAD_DIM + f];
    float pi = rp[b * HEAD_DIM + NUM_FREQS + f];
    float w  = wraw[b * NUM_FREQS + f];
    float sp = fmaxf(w, 0.0f) + log1pf(expf(-fabsf(w)));   // stable softplus
    probeA[idx] = make_float4(-2.0f * pr, -2.0f * pi,
                              fmaf(pr, pr, pi * pi), -sp);
    probeM[idx] = mw[b * NUM_FREQS + f];
}

// ---------------------------------------------------------------------------
// Main: block = 256 threads (4 waves); block owns 16 queries; wave w owns
// j in [4w, 4w+4); lane covers bins (lane, lane+64) -> 8 outputs per lane.
// In-block q-prep (padded sri, 4-way scatter). Main loop: expanded distance
// s = C'' + qm^2 - 2Pr*qr - 2Pi*qi, v_sqrt_f32.
// HAND MODULO-2 SCHEDULE: two statically-named register sets A/B ping-pong —
// issue B(f+1); SB; compute A(f); issue A(f+2); SB; compute B(f+1).
// Empirically the best structure found (R20): 93% VALU-issue efficiency
// (208 math cy / 224 busy cy per wave-f), sqrt-dominated.
// ---------------------------------------------------------------------------
__global__ __launch_bounds__(256, 4) void main_kernel(
        const float4* __restrict__ probeA,
        const float*  __restrict__ probeM,
        const float*  __restrict__ Q,
        const float*  __restrict__ bias,
        float*        __restrict__ out) {
    __shared__ float2 sri[NUM_FREQS + 1][SRP];   // padded, +1 guard row
    __shared__ float  sqm[NUM_FREQS + 1][NQB];   // linear, +1 guard row

    const int tid   = threadIdx.x;
    const int qbase = blockIdx.x * NQB;

    // ---- in-block q-prep ----
    {
        const float4* Qb = reinterpret_cast<const float4*>(Q + (size_t)qbase * HEAD_DIM);
        float4 v1 = Qb[tid];
        float4 v2 = Qb[tid + 256];
        const int c  = tid & 31;
        const int r1 = tid >> 5;
        const int r2 = r1 + 8;

        float s1 = fmaf(v1.x, v1.x, fmaf(v1.y, v1.y, fmaf(v1.z, v1.z, v1.w * v1.w)));
        float s2 = fmaf(v2.x, v2.x, fmaf(v2.y, v2.y, fmaf(v2.z, v2.z, v2.w * v2.w)));
        #pragma unroll
        for (int off = 1; off < 32; off <<= 1) {   // reduce within 32-lane group
            s1 += __shfl_xor(s1, off);
            s2 += __shfl_xor(s2, off);
        }
        float inv1 = 1.0f / (__builtin_amdgcn_sqrtf(s1) + EPS);
        float inv2 = 1.0f / (__builtin_amdgcn_sqrtf(s2) + EPS);

        const float a1[4] = { v1.x, v1.y, v1.z, v1.w };
        const float a2[4] = { v2.x, v2.y, v2.z, v2.w };
        if (c < 16) {                          // real parts: rows d = 4c+k
            #pragma unroll
            for (int k = 0; k < 4; k++) {
                int row = 4 * c + k;
                sri[row][r1].x = a1[k] * inv1;
                sri[row][r2].x = a2[k] * inv2;
            }
        } else {                               // imag parts: rows 4(c-16)+k
            #pragma unroll
            for (int k = 0; k < 4; k++) {
                int row = 4 * (c - 16) + k;
                sri[row][r1].y = a1[k] * inv1;
                sri[row][r2].y = a2[k] * inv2;
            }
        }
    }
    __syncthreads();
    #pragma unroll
    for (int i = 0; i < 4; i++) {
        int e = i * 256 + tid;
        int f = e >> 4, j = e & 15;
        float2 ri = sri[f][j];
        sqm[f][j] = __builtin_amdgcn_sqrtf(fmaf(ri.x, ri.x, fmaf(ri.y, ri.y, EPS)));
    }
    __syncthreads();

    const int lane = tid & 63;
    const int wave = tid >> 6;
    const int jb   = wave * 4;               // this wave's j-chunk base

    float b0 = bias[lane];
    float b1 = bias[64 + lane];

    float acc0[4], acc1[4];
    #pragma unroll
    for (int p = 0; p < 4; p++) { acc0[p] = 0.0f; acc1[p] = 0.0f; }

    const float4* pA = probeA + lane;        // walks +128 float4 per f
    const float*  pM = probeM + lane;

// compute one f using a named register set (4 j x 2 bins)
#define CSTEP(P0_, P1_, w0_, w1_, qa_, qb_, qc_, qd_, qm_)                   \
    {                                                                        \
        const float qrv[4] = { qa_.x, qb_.x, qc_.x, qd_.x };                 \
        const float qiv[4] = { qa_.y, qb_.y, qc_.y, qd_.y };                 \
        const float qmv[4] = { qm_.x, qm_.y, qm_.z, qm_.w };                 \
        _Pragma("unroll")                                                    \
        for (int p = 0; p < 4; p++) {                                        \
            float qr = qrv[p], qi = qiv[p], qm = qmv[p];                     \
            float a0 = fmaf(qm, qm, P0_.z);                                  \
            a0 = fmaf(P0_.x, qr, a0);                                        \
            a0 = fmaf(P0_.y, qi, a0);                                        \
            float d0 = __builtin_amdgcn_sqrtf(a0);                           \
            acc0[p] = fmaf(d0, P0_.w, fmaf(qm, w0_, acc0[p]));               \
            float a1 = fmaf(qm, qm, P1_.z);                                  \
            a1 = fmaf(P1_.x, qr, a1);                                        \
            a1 = fmaf(P1_.y, qi, a1);                                        \
            float d1 = __builtin_amdgcn_sqrtf(a1);                           \
            acc1[p] = fmaf(d1, P1_.w, fmaf(qm, w1_, acc1[p]));               \
        }                                                                    \
    }

    // Prologue: set A <- f = 0.
    float4 A_P0 = pA[0], A_P1 = pA[64];
    float  A_w0 = pM[0], A_w1 = pM[64];
    float2 A_q0 = sri[0][jb],     A_q1 = sri[0][jb + 1];
    float2 A_q2 = sri[0][jb + 2], A_q3 = sri[0][jb + 3];
    float4 A_qm = *reinterpret_cast<const float4*>(&sqm[0][jb]);
    pA += NUM_BINS; pM += NUM_BINS;

    #pragma unroll 2
    for (int g = 0; g < NUM_FREQS / 2; ++g) {
        const int f1 = 2 * g + 1;
        // ---- issue set B <- f1 ----
        float4 B_P0 = pA[0], B_P1 = pA[64];
        float  B_w0 = pM[0], B_w1 = pM[64];
        float2 B_q0 = sri[f1][jb],     B_q1 = sri[f1][jb + 1];
        float2 B_q2 = sri[f1][jb + 2], B_q3 = sri[f1][jb + 3];
        float4 B_qm = *reinterpret_cast<const float4*>(&sqm[f1][jb]);
        pA += NUM_BINS; pM += NUM_BINS;
        __builtin_amdgcn_sched_barrier(0);
        // ---- compute A (f1-1) ----
        CSTEP(A_P0, A_P1, A_w0, A_w1, A_q0, A_q1, A_q2, A_q3, A_qm);

        // ---- issue set A <- f1+1 (g=31: row 64 = guard / probeM margin) ----
        A_P0 = pA[0]; A_P1 = pA[64];
        A_w0 = pM[0]; A_w1 = pM[64];
        A_q0 = sri[f1 + 1][jb];     A_q1 = sri[f1 + 1][jb + 1];
        A_q2 = sri[f1 + 1][jb + 2]; A_q3 = sri[f1 + 1][jb + 3];
        A_qm = *reinterpret_cast<const float4*>(&sqm[f1 + 1][jb]);
        pA += NUM_BINS; pM += NUM_BINS;
        __builtin_amdgcn_sched_barrier(0);
        // ---- compute B (f1) ----
        CSTEP(B_P0, B_P1, B_w0, B_w1, B_q0, B_q1, B_q2, B_q3, B_qm);
    }
#undef CSTEP

    #pragma unroll
    for (int p = 0; p < 4; p++) {
        size_t row = (size_t)(qbase + jb + p) * NUM_BINS;
        out[row + lane]      = acc0[p] + b0;     // coalesced
        out[row + 64 + lane] = acc1[p] + b1;     // coalesced
    }
}

// ---------------------------------------------------------------------------
// Fallback (only if ws_size is too small): fully self-contained, slower.
// ---------------------------------------------------------------------------
__global__ void fallback_kernel(const float* __restrict__ Q,
                                const float* __restrict__ rp,
                                const float* __restrict__ wraw,
                                const float* __restrict__ mw,
                                const float* __restrict__ bias,
                                float* __restrict__ out) {
    __shared__ float qn[HEAD_DIM];
    __shared__ float qmag[NUM_FREQS];
    __shared__ float red[NUM_BINS];
    const int t = threadIdx.x;
    const int q = blockIdx.x;

    float v = Q[(size_t)q * HEAD_DIM + t];
    red[t] = v * v;
    __syncthreads();
    for (int s = 64; s > 0; s >>= 1) {
        if (t < s) red[t] += red[t + s];
        __syncthreads();
    }
    float inv = 1.0f / (__builtin_amdgcn_sqrtf(red[0]) + EPS);
    qn[t] = v * inv;
    __syncthreads();
    if (t < NUM_FREQS) {
        float a = qn[t], c = qn[t + NUM_FREQS];
        qmag[t] = __builtin_amdgcn_sqrtf(fmaf(a, a, fmaf(c, c, EPS)));
    }
    __syncthreads();

    const int b = t;
    float acc = 0.0f;
    for (int f = 0; f < NUM_FREQS; f++) {
        float pr = rp[(size_t)b * HEAD_DIM + f];
        float pi = rp[(size_t)b * HEAD_DIM + NUM_FREQS + f];
        float w  = wraw[(size_t)b * NUM_FREQS + f];
        float ew = -(fmaxf(w, 0.0f) + log1pf(expf(-fabsf(w))));
        float er = pr - qn[f];
        float ei = pi - qn[f + NUM_FREQS];
        float d  = __builtin_amdgcn_sqrtf(fmaf(er, er, fmaf(ei, ei, EPS)));
        acc = fmaf(d, ew, fmaf(qmag[f], mw[(size_t)b * NUM_FREQS + f], acc));
    }
    out[(size_t)q * NUM_BINS + b] = acc + bias[b];
}

// ---------------------------------------------------------------------------
extern "C" void kernel_launch(void* const* d_in, const int* in_sizes, int n_in,
                              void* d_out, int out_size, void* d_ws, size_t ws_size,
                              hipStream_t stream) {
    const float* Q    = (const float*)d_in[0];
    const float* rp   = (const float*)d_in[1];
    const float* wraw = (const float*)d_in[2];
    const float* mw   = (const float*)d_in[3];
    const float* bias = (const float*)d_in[4];
    float* out = (float*)d_out;

    const size_t pABytes = (size_t)NUM_FREQS * NUM_BINS * sizeof(float4);  // 128 KiB
    const size_t pMBytes = (size_t)NUM_FREQS * NUM_BINS * sizeof(float);   //  32 KiB
    const size_t need    = pABytes + pMBytes + 8192;   // + margin for f=64 prefetch

    if (ws_size >= need) {
        float4* probeA = (float4*)d_ws;
        float*  probeM = (float*)((char*)d_ws + pABytes);

        hipLaunchKernelGGL(prep_probe, dim3(32), dim3(256), 0, stream,
                           rp, wraw, mw, probeA, probeM);
        hipLaunchKernelGGL(main_kernel, dim3(NUM_QUERIES / NQB), dim3(256), 0,
                           stream, probeA, probeM, Q, bias, out);
    } else {
        hipLaunchKernelGGL(fallback_kernel, dim3(NUM_QUERIES), dim3(NUM_BINS), 0,
                           stream, Q, rp, wraw, mw, bias, out);
    }
}